// Round 1
// 212.341 us; speedup vs baseline: 1.0243x; 1.0243x over previous
//
#include <hip/hip_runtime.h>

// Problem constants (from reference setup_inputs)
constexpr int NA = 256;   // N_AGENTS
constexpr int B  = 64;    // BATCH
constexpr int S  = 20;    // SEQ
constexpr int H  = 128;   // HID

// Grid: 256 blocks = 64 batches x 4 agent-chunks of 64 agents -> exactly 1 block/CU.
// Block: 1024 threads = 16 waves; each wave owns 4 agents (16*4 = 64).
//
// Plan:
//  - Stage this batch's 256 last-timestep positions in LDS (2 KB).
//  - Stage the full h_last[:, b, :] (256 rows x 512 B = 128 KB) into LDS in 4
//    pipelined chunks of 64 rows. Reg-staged (global->VGPR->ds_write); the
//    global loads for chunk c+1 are issued right AFTER the chunk-c barrier and
//    consumed at the START of the next iteration, so HBM/L2 latency hides under
//    the chunk-c gather. Chunks occupy disjoint LDS -> ONE barrier per chunk.
//  - Neighbor masks (four 64-bit ballot words per agent) need only positions,
//    so all 16 words per wave are computed while chunk-0 loads are in flight.
//  - Gather reads rows from LDS: masks are wave-uniform (SGPR) -> scalar
//    s_ff1/s_andn2 walk, 32-bit LDS addressing, ds_read_b64 (2-way bank
//    aliasing = free). 4 independent walks interleaved for ILP.
// Numerics: identical to the passing kernel — __f*_rn, no FMA contraction,
// correctly-rounded sqrt, inclusive <=, __fdiv_rn epilogue.
__global__ __launch_bounds__(1024, 4) void social_pool_kernel(
    const float* __restrict__ h,    // (NA, B, S, H)
    const float* __restrict__ p,    // (NA, B, S, 2)
    const float* __restrict__ rptr, // scalar radius
    float* __restrict__ out)        // (NA, B, H)
{
    const int bid   = blockIdx.x;
    const int inner = bid & 63;
    // Bijective bit-swap so the 4 blocks sharing a batch b have equal bid%8
    // (same XCD under round-robin dispatch) -> staged h rows L2-hit.
    const int b     = ((inner & 7) << 3) | (inner >> 3);
    const int ic    = bid >> 6;     // agent chunk 0..3
    const int tid   = threadIdx.x;
    const int wave  = tid >> 6;     // 0..15
    const int lane  = tid & 63;

    __shared__ float hs[NA * H];    // 128 KB, row j at hs + j*H (512 B rows)
    __shared__ float px[NA];
    __shared__ float py[NA];

    // ---- stage positions (first 256 threads; scattered 8 B loads, L2-hit) ----
    if (tid < NA) {
        const float2 pj = *(const float2*)(p + (((size_t)(tid * B + b)) * S + (S - 1)) * 2);
        px[tid] = pj.x;
        py[tid] = pj.y;
    }
    __syncthreads();

    const float r = *rptr;

    // ---- staging geometry: per wave, per chunk: 4 rows = 2 KB (2x float4/lane) ----
    const int colf = (lane & 31) << 2;            // float column within a row
    const int rsub = (wave << 2) + (lane >> 5);   // row-within-chunk, part 0 (part 1 = +2)
    const size_t jstr = (size_t)B * S * H;        // float stride between agents
    const size_t boff = (size_t)b * S * H + (size_t)(S - 1) * H;

    auto gsrc = [&](int j) -> const float4* {
        return (const float4*)(h + (size_t)j * jstr + boff + colf);
    };

    // Issue chunk-0 loads; their latency overlaps the ballot phase below.
    float4 ra = *gsrc(rsub);
    float4 rb = *gsrc(rsub + 2);

    // ---- neighbor masks: four 64-bit words per agent (positions only) ----
    const int i0 = (ic << 6) + (wave << 2);       // first of this wave's 4 agents
    unsigned long long m[4][4];                   // [agent][word], wave-uniform
    #pragma unroll
    for (int a = 0; a < 4; ++a) {
        const float xi = px[i0 + a];
        const float yi = py[i0 + a];
        #pragma unroll
        for (int k = 0; k < 4; ++k) {
            const int j = (k << 6) + lane;
            const float dx   = __fsub_rn(xi, px[j]);
            const float dy   = __fsub_rn(yi, py[j]);
            const float d2   = __fadd_rn(__fmul_rn(dx, dx), __fmul_rn(dy, dy));
            const float dist = __fsqrt_rn(d2);
            m[a][k] = __ballot(dist <= r);
            if (k == ic) m[a][k] &= ~(1ull << ((i0 + a) & 63));  // static idx, excl. self
        }
    }
    int n[4];
    #pragma unroll
    for (int a = 0; a < 4; ++a)
        n[a] = __popcll(m[a][0]) + __popcll(m[a][1]) + __popcll(m[a][2]) + __popcll(m[a][3]);

    // ---- pipelined stage + gather over 4 chunks of 64 rows ----
    const int lo2 = lane << 1;                    // this lane's 2 channels
    float ax[4] = {0.f, 0.f, 0.f, 0.f};
    float ay[4] = {0.f, 0.f, 0.f, 0.f};

    #pragma unroll
    for (int c = 0; c < 4; ++c) {
        // publish chunk c (compiler inserts the vmcnt wait on ra/rb here)
        {
            const int j0 = (c << 6) + rsub;
            *(float4*)(hs + j0 * H + colf)       = ra;
            *(float4*)(hs + (j0 + 2) * H + colf) = rb;
        }
        __syncthreads();   // chunk c visible; no outstanding globals -> no drain stall
        if (c < 3) {       // issue chunk c+1 AFTER the barrier: flies during gather-c
            const int j0 = ((c + 1) << 6) + rsub;
            ra = *gsrc(j0);
            rb = *gsrc(j0 + 2);
        }

        // gather chunk c from LDS: 4 interleaved scalar mask-walks
        unsigned long long g0 = m[0][c], g1 = m[1][c], g2 = m[2][c], g3 = m[3][c];
        const float* base = hs + (c << 6) * H + lo2;
        while (g0 | g1 | g2 | g3) {
            float2 v0, v1, v2, v3;
            const bool h0 = g0 != 0ull, h1 = g1 != 0ull, h2 = g2 != 0ull, h3 = g3 != 0ull;
            if (h0) { const int j = __builtin_ctzll(g0); g0 &= g0 - 1ull; v0 = *(const float2*)(base + j * H); }
            if (h1) { const int j = __builtin_ctzll(g1); g1 &= g1 - 1ull; v1 = *(const float2*)(base + j * H); }
            if (h2) { const int j = __builtin_ctzll(g2); g2 &= g2 - 1ull; v2 = *(const float2*)(base + j * H); }
            if (h3) { const int j = __builtin_ctzll(g3); g3 &= g3 - 1ull; v3 = *(const float2*)(base + j * H); }
            if (h0) { ax[0] += v0.x; ay[0] += v0.y; }
            if (h1) { ax[1] += v1.x; ay[1] += v1.y; }
            if (h2) { ax[2] += v2.x; ay[2] += v2.y; }
            if (h3) { ax[3] += v3.x; ay[3] += v3.y; }
        }
    }

    // ---- epilogue: divide by clipped count, coalesced 512 B store per agent ----
    #pragma unroll
    for (int a = 0; a < 4; ++a) {
        const int i = i0 + a;
        const float cnt = (float)(n[a] > 0 ? n[a] : 1);
        float2 o;
        o.x = __fdiv_rn(ax[a], cnt);
        o.y = __fdiv_rn(ay[a], cnt);
        *(float2*)(out + ((size_t)i * B + b) * H + lo2) = o;
    }
}

extern "C" void kernel_launch(void* const* d_in, const int* in_sizes, int n_in,
                              void* d_out, int out_size, void* d_ws, size_t ws_size,
                              hipStream_t stream) {
    const float* h    = (const float*)d_in[0];
    const float* p    = (const float*)d_in[1];
    const float* rptr = (const float*)d_in[2];
    float* out        = (float*)d_out;

    (void)in_sizes; (void)n_in; (void)out_size; (void)d_ws; (void)ws_size;

    constexpr int BLOCKS = B * (NA / 64);   // 64 batches x 4 agent-chunks = 256
    social_pool_kernel<<<dim3(BLOCKS), dim3(1024), 0, stream>>>(h, p, rptr, out);
}